// Round 10
// baseline (1582.458 us; speedup 1.0000x reference)
//
#include <hip/hip_runtime.h>
#include <hip/hip_cooperative_groups.h>
namespace cg = cooperative_groups;

#define LDA 68  // padded leading dim for 64-wide fp32 LDS tiles

typedef __attribute__((ext_vector_type(8))) short bf16x8;
typedef __attribute__((ext_vector_type(4))) float floatx4;

// bf16 helpers (RNE)
__device__ __forceinline__ unsigned short f2bf(float f)
{
    union { float f; unsigned int u; } v; v.f = f;
    unsigned int r = (v.u + 0x7fffu + ((v.u >> 16) & 1u)) >> 16;
    return (unsigned short)r;
}
__device__ __forceinline__ float bf2f(unsigned short b)
{
    union { unsigned int u; float f; } v; v.u = ((unsigned int)b) << 16;
    return v.f;
}

// acc += (Ah+Al) * (Bh+Bl), dropping Al*Bl  (~16-bit-mantissa GEMM)
#define MFMA3(accv, ah, al, bh, bl)                                              \
    accv = __builtin_amdgcn_mfma_f32_16x16x32_bf16(ah, bh, accv, 0, 0, 0);       \
    accv = __builtin_amdgcn_mfma_f32_16x16x32_bf16(al, bh, accv, 0, 0, 0);       \
    accv = __builtin_amdgcn_mfma_f32_16x16x32_bf16(ah, bl, accv, 0, 0, 0);

// B-fragment read from prepped global weights ([n][64k] shorts, 16B aligned)
#define BFRAG(P, n, kc, qd) (*(const bf16x8*)((P) + ((n) << 6) + (kc) * 32 + (qd) * 8))

__device__ __forceinline__ void pack_pair(const float* f, bf16x8& hi, bf16x8& lo)
{
#pragma unroll
    for (int j = 0; j < 8; ++j) {
        unsigned short hb = f2bf(f[j]);
        hi[j] = (short)hb;
        lo[j] = (short)f2bf(f[j] - bf2f(hb));
    }
}

// ---------------------------------------------------------------- weight prep (once per launch)
// mats: 0 = proj_W, 1..12 = mlp_W[m*3+l], 13 = Wv.

__global__ void k_prep(const float* __restrict__ pW, const float* __restrict__ mlpW,
                       const float* __restrict__ Wv,
                       short* __restrict__ preH, short* __restrict__ preL)
{
    int mat = blockIdx.x;
    const float* Wg = (mat == 0) ? pW : ((mat <= 12) ? mlpW + (size_t)(mat - 1) * 4096 : Wv);
    int t = threadIdx.x;
    short* dh = preH + (size_t)mat * 4096;
    short* dl = preL + (size_t)mat * 4096;
#pragma unroll
    for (int i = 0; i < 16; ++i) {
        int idx = i * 256 + t;
        int k = idx >> 6, n = idx & 63;
        float w = Wg[idx];  // idx = k*64+n, coalesced
        unsigned short hb = f2bf(w);
        dh[n * 64 + k] = (short)hb;
        dl[n * 64 + k] = (short)f2bf(w - bf2f(hb));
    }
}

// ---------------------------------------------------------------- small VALU GEMM helpers (k_embed/k_logits only)

__device__ __forceinline__ void stage_tile(const float* __restrict__ g, int base, int nrows,
                                           float* __restrict__ Ash, int t)
{
#pragma unroll
    for (int i = 0; i < 4; ++i) {
        int idx = i * 256 + t;
        int r = idx >> 4;
        int c = (idx & 15) << 2;
        float4 v = make_float4(0.f, 0.f, 0.f, 0.f);
        int row = base + r;
        if (row < nrows) v = *(const float4*)(g + (size_t)row * 64 + c);
        *(float4*)(Ash + r * LDA + c) = v;
    }
}

__device__ __forceinline__ void stage_w(const float* __restrict__ g, int ldg,
                                        float* __restrict__ Wsh, int t)
{
#pragma unroll
    for (int i = 0; i < 4; ++i) {
        int idx = i * 256 + t;
        int k = idx >> 4;
        int f = (idx & 15) << 2;
        *(float4*)(Wsh + k * 64 + f) = *(const float4*)(g + (size_t)k * ldg + f);
    }
}

__device__ __forceinline__ void gemm_tile(const float* __restrict__ Ash, const float* __restrict__ Wsh,
                                          float acc[4][4], int n0, int f0)
{
#pragma unroll
    for (int k0 = 0; k0 < 64; k0 += 4) {
        float a[4][4], w[4][4];
#pragma unroll
        for (int i = 0; i < 4; ++i) {
            float4 t4 = *(const float4*)(Ash + (n0 + i) * LDA + k0);
            a[i][0] = t4.x; a[i][1] = t4.y; a[i][2] = t4.z; a[i][3] = t4.w;
        }
#pragma unroll
        for (int k = 0; k < 4; ++k) {
            float4 t4 = *(const float4*)(Wsh + (k0 + k) * 64 + f0);
            w[k][0] = t4.x; w[k][1] = t4.y; w[k][2] = t4.z; w[k][3] = t4.w;
        }
#pragma unroll
        for (int i = 0; i < 4; ++i)
#pragma unroll
            for (int k = 0; k < 4; ++k)
#pragma unroll
                for (int j = 0; j < 4; ++j)
                    acc[i][j] = fmaf(a[i][k], w[k][j], acc[i][j]);
    }
}

// ---------------------------------------------------------------- CSR build, partitioned by source tile (4 tiles)

__global__ void k_count4(const int* __restrict__ src, const int* __restrict__ dst,
                         int* __restrict__ cnt4, int E, int N)
{
    for (int e = blockIdx.x * 256 + threadIdx.x; e < E; e += gridDim.x * 256) {
        int s = src[e], d = dst[e];
        int tl = s / 25000;
        atomicAdd(&cnt4[(size_t)tl * N + d], 1);
    }
}

__global__ void k_scan1b(const int* __restrict__ cnt, int* __restrict__ bsum, int n4)
{
    __shared__ int red[256];
    int t = threadIdx.x;
    int i = blockIdx.x * 256 + t;
    int s = 0;
    if (i < n4) {
        int4 v = ((const int4*)cnt)[i];
        s = v.x + v.y + v.z + v.w;
    }
    red[t] = s;
    __syncthreads();
    for (int off = 128; off; off >>= 1) {
        if (t < off) red[t] += red[t + off];
        __syncthreads();
    }
    if (t == 0) bsum[blockIdx.x] = red[0];
}

__global__ void k_scan2(const int* __restrict__ bsum, int* __restrict__ boff,
                        int nb, int* __restrict__ rowptrEnd)
{
    __shared__ int sc[512];
    int t = threadIdx.x;
    int v = (t < nb) ? bsum[t] : 0;
    sc[t] = v;
    __syncthreads();
    for (int off = 1; off < 512; off <<= 1) {
        int u = (t >= off) ? sc[t - off] : 0;
        __syncthreads();
        sc[t] += u;
        __syncthreads();
    }
    if (t < nb) boff[t] = sc[t] - v;
    if (t == nb - 1) *rowptrEnd = sc[t];
}

__global__ void k_scan3b(int* __restrict__ cnt, const int* __restrict__ boff,
                         int* __restrict__ rowptr, int n4)
{
    __shared__ int sc[256];
    int t = threadIdx.x;
    int i = blockIdx.x * 256 + t;
    int4 v = make_int4(0, 0, 0, 0);
    if (i < n4) v = ((const int4*)cnt)[i];
    int tot = v.x + v.y + v.z + v.w;
    sc[t] = tot;
    __syncthreads();
    for (int off = 1; off < 256; off <<= 1) {
        int u = (t >= off) ? sc[t - off] : 0;
        __syncthreads();
        sc[t] += u;
        __syncthreads();
    }
    if (i < n4) {
        int ex = boff[blockIdx.x] + sc[t] - tot;
        int4 rp;
        rp.x = ex; rp.y = ex + v.x; rp.z = rp.y + v.y; rp.w = rp.z + v.z;
        ((int4*)rowptr)[i] = rp;
        ((int4*)cnt)[i] = make_int4(0, 0, 0, 0);
    }
}

__global__ void k_fill4(const int* __restrict__ src, const int* __restrict__ dst,
                        const int* __restrict__ rowptr4, int* __restrict__ cursor,
                        int* __restrict__ col4, int E, int N)
{
    for (int e = blockIdx.x * 256 + threadIdx.x; e < E; e += gridDim.x * 256) {
        int s = src[e], d = dst[e];
        int tl = s / 25000;
        size_t r = (size_t)tl * N + d;
        int p = atomicAdd(&cursor[r], 1);
        col4[rowptr4[r] + p] = s;
    }
}

// ---------------------------------------------------------------- feature BN stats (4-way replicated atomics)

__global__ void k_xstats(const float* __restrict__ x, float* __restrict__ stats, int N)
{
    __shared__ float rs[256], rq[256];
    int t = threadIdx.x;
    int f = t & 63, rg = t >> 6;
    float s = 0.f, q = 0.f;
    for (int r = blockIdx.x * 4 + rg; r < N; r += gridDim.x * 4) {
        float v = x[(size_t)r * 64 + f];
        s += v; q += v * v;
    }
    rs[rg * 64 + f] = s; rq[rg * 64 + f] = q;
    __syncthreads();
    if (t < 64) {
        float ts = rs[t] + rs[64 + t] + rs[128 + t] + rs[192 + t];
        float tq = rq[t] + rq[64 + t] + rq[128 + t] + rq[192 + t];
        int rep = (blockIdx.x & 3) * 128;
        atomicAdd(&stats[rep + t], ts);
        atomicAdd(&stats[rep + 64 + t], tq);
    }
}

__device__ __forceinline__ void finalize_lds(const float* __restrict__ stats,
                                             const float* __restrict__ gamma,
                                             const float* __restrict__ beta,
                                             float* __restrict__ SS, int t, float invN)
{
    if (t < 64) {
        float su = stats[t] + stats[128 + t] + stats[256 + t] + stats[384 + t];
        float qu = stats[64 + t] + stats[192 + t] + stats[320 + t] + stats[448 + t];
        float mu = su * invN;
        float var = qu * invN - mu * mu;
        float sc = gamma[t] * rsqrtf(var + 1e-5f);
        SS[t] = sc;
        SS[64 + t] = beta[t] - mu * sc;
    }
}

// ---------------------------------------------------------------- input projection

__global__ void __launch_bounds__(256, 4)
k_proj(const float* __restrict__ x, const float* __restrict__ stats,
       const float* __restrict__ fn_g, const float* __restrict__ fn_b,
       const short* __restrict__ WH, const short* __restrict__ WL,
       const float* __restrict__ b,
       float* __restrict__ res, unsigned short* __restrict__ hbh,
       int N, float invN)
{
    __shared__ float ScSh[128];
    __shared__ float BiasSh[64];
    int t = threadIdx.x;
    int wave = t >> 6, lane = t & 63;
    int m = lane & 15, qd = lane >> 4;
    int base = blockIdx.x * 64;
    int nodeA = base + wave * 16 + m;

    finalize_lds(stats, fn_g, fn_b, ScSh, t, invN);
    if (t < 64) BiasSh[t] = b[t];
    __syncthreads();

    int rowc = min(nodeA, N - 1);
    bf16x8 ah[2], al[2];
#pragma unroll
    for (int kc = 0; kc < 2; ++kc) {
        floatx4 x0 = *(const floatx4*)(x + (size_t)rowc * 64 + kc * 32 + qd * 8);
        floatx4 x1 = *(const floatx4*)(x + (size_t)rowc * 64 + kc * 32 + qd * 8 + 4);
        float av[8];
#pragma unroll
        for (int j = 0; j < 8; ++j) {
            int k = kc * 32 + qd * 8 + j;
            float xv = (j < 4) ? x0[j] : x1[j - 4];
            av[j] = xv * ScSh[k] + ScSh[64 + k];
        }
        pack_pair(av, ah[kc], al[kc]);
    }

    floatx4 acc[4];
#pragma unroll
    for (int tt = 0; tt < 4; ++tt) {
        float bv = BiasSh[tt * 16 + m];
        acc[tt] = (floatx4){bv, bv, bv, bv};
    }
#pragma unroll
    for (int kc = 0; kc < 2; ++kc)
#pragma unroll
        for (int tt = 0; tt < 4; ++tt) {
            bf16x8 bh = BFRAG(WH, tt * 16 + m, kc, qd);
            bf16x8 bl = BFRAG(WL, tt * 16 + m, kc, qd);
            MFMA3(acc[tt], ah[kc], al[kc], bh, bl);
        }

#pragma unroll
    for (int tt = 0; tt < 4; ++tt)
#pragma unroll
        for (int r = 0; r < 4; ++r) {
            int node = base + wave * 16 + qd * 4 + r;
            if (node < N) {
                int col = tt * 16 + m;
                float v = fmaxf(acc[tt][r], 0.f);
                res[(size_t)node * 64 + col] = v;
                hbh[(size_t)node * 64 + col] = f2bf(v);
            }
        }
}

// ---------------------------------------------------------------- cooperative GNN stack (8 convs, tile-phased gather)
// grid = 896 blocks (capacity 1024 at 4 blocks/CU — 128-block margin vs r9's exact-fit failure).
// Each block owns groups {blockIdx, blockIdx+896}. Tile-phased gather keeps the 3.2MB
// active src tile L2-resident on every XCD. BN fused via grid.sync; z never hits global.

#define GNN_GRID 896

__global__ void __launch_bounds__(256, 4)
k_gnn(unsigned short* __restrict__ hbh, unsigned short* __restrict__ hbl,
      const int* __restrict__ rowptr4, const int* __restrict__ col4,
      const short* __restrict__ preH, const short* __restrict__ preL,
      const float* __restrict__ mlpb, const float* __restrict__ ngm,
      const float* __restrict__ nbt, float* __restrict__ res,
      float* __restrict__ stats, int N, float invN)
{
    cg::grid_group grid = cg::this_grid();
    __shared__ __align__(16) float Aint[2 * 64 * 68];
    __shared__ float BiasSh[192];
    __shared__ float SS[128];
    const int NG = (N + 63) >> 6;  // 1563
    int t = threadIdx.x;
    int wave = t >> 6, lane = t & 63;
    int m = lane & 15, qd = lane >> 4;

#pragma unroll 1
    for (int conv = 0; conv < 8; ++conv) {
        int mm = conv >> 1, cc = conv & 1;
        const short* WH = preH + (size_t)(1 + mm * 3) * 4096;
        const short* WL = preL + (size_t)(1 + mm * 3) * 4096;
        if (t < 192) BiasSh[t] = mlpb[mm * 192 + t];

        // self-init Aw (bf16 self term)
#pragma unroll 1
        for (int s = 0; s < 2; ++s) {
            int grp = blockIdx.x + s * GNN_GRID;
            if (grp < NG) {
                float* Aw = Aint + s * 4352 + wave * 1088;
                int base = grp * 64;
#pragma unroll
                for (int i = 0; i < 16; ++i) {
                    int node = base + wave * 16 + i;
                    Aw[i * 68 + lane] = (node < N) ? bf2f(hbh[(size_t)node * 64 + lane]) : 0.f;
                }
            }
        }

        // tile-phased gather
#pragma unroll 1
        for (int tl = 0; tl < 4; ++tl) {
#pragma unroll 1
            for (int s = 0; s < 2; ++s) {
                int grp = blockIdx.x + s * GNN_GRID;
                if (grp < NG) {
                    float* Aw = Aint + s * 4352 + wave * 1088;
                    int base = grp * 64;
                    int wstart = base + wave * 16;
                    // one vector load of this wave's 17 row pointers for tile tl
                    int rs = rowptr4[(size_t)tl * N + min(wstart + min(lane, 16), N)];
#pragma unroll 1
                    for (int i = 0; i < 16; ++i) {
                        int node = wstart + i;
                        int e0 = __shfl(rs, i);
                        int e1 = __shfl(rs, i + 1);
                        if (node < N && e0 < e1) {
                            float a = Aw[i * 68 + lane];
                            int e = e0;
                            for (; e + 4 <= e1; e += 4) {
                                int s0 = col4[e + 0], s1 = col4[e + 1];
                                int s2 = col4[e + 2], s3 = col4[e + 3];
                                a += (bf2f(hbh[(size_t)s0 * 64 + lane]) + bf2f(hbh[(size_t)s1 * 64 + lane]))
                                   + (bf2f(hbh[(size_t)s2 * 64 + lane]) + bf2f(hbh[(size_t)s3 * 64 + lane]));
                            }
                            for (; e < e1; ++e)
                                a += bf2f(hbh[(size_t)col4[e] * 64 + lane]);
                            Aw[i * 68 + lane] = a;
                        }
                    }
                }
            }
            if (tl < 3) grid.sync();  // phase-lock the active tile in L2
        }
        __syncthreads();

        // 3-layer MFMA MLP per slot (z stays in registers; slot loop unrolled for static accg)
        floatx4 accg[2][4];
#pragma unroll
        for (int s = 0; s < 2; ++s) {
            int grp = blockIdx.x + s * GNN_GRID;
            bool valid = grp < NG;  // block-uniform
            float* Aw = Aint + s * 4352 + wave * 1088;
#pragma unroll 1
            for (int l = 0; l < 3; ++l) {
                const short* LH = WH + l * 4096;
                const short* LL = WL + l * 4096;
                if (valid) {
#pragma unroll
                    for (int tt = 0; tt < 4; ++tt) {
                        float bv = BiasSh[l * 64 + tt * 16 + m];
                        accg[s][tt] = (floatx4){bv, bv, bv, bv};
                    }
#pragma unroll
                    for (int kc = 0; kc < 2; ++kc) {
                        floatx4 x0 = *(const floatx4*)(Aw + m * 68 + kc * 32 + qd * 8);
                        floatx4 x1 = *(const floatx4*)(Aw + m * 68 + kc * 32 + qd * 8 + 4);
                        float av[8];
#pragma unroll
                        for (int j = 0; j < 8; ++j) av[j] = (j < 4) ? x0[j] : x1[j - 4];
                        bf16x8 ah, al;
                        pack_pair(av, ah, al);
#pragma unroll
                        for (int tt = 0; tt < 4; ++tt) {
                            bf16x8 bh = BFRAG(LH, tt * 16 + m, kc, qd);
                            bf16x8 bl = BFRAG(LL, tt * 16 + m, kc, qd);
                            MFMA3(accg[s][tt], ah, al, bh, bl);
                        }
                    }
                }
                if (l < 2) {
                    __syncthreads();
                    if (valid) {
#pragma unroll
                        for (int tt = 0; tt < 4; ++tt)
#pragma unroll
                            for (int r = 0; r < 4; ++r)
                                Aw[(qd * 4 + r) * 68 + tt * 16 + m] = fmaxf(accg[s][tt][r], 0.f);
                    }
                    __syncthreads();
                }
            }
        }

        // BN partial stats (both slots), 4-replica atomics
        __syncthreads();
        float* SW = Aint;
        float* stc = stats + (size_t)(1 + conv) * 512;
#pragma unroll
        for (int tt = 0; tt < 4; ++tt) {
            float s2 = 0.f, q2 = 0.f;
#pragma unroll
            for (int s = 0; s < 2; ++s) {
                int grp = blockIdx.x + s * GNN_GRID;
#pragma unroll
                for (int r = 0; r < 4; ++r) {
                    int node = grp * 64 + wave * 16 + qd * 4 + r;
                    if (grp < NG && node < N) {
                        float v = accg[s][tt][r];
                        s2 += v; q2 += v * v;
                    }
                }
            }
            SW[(tt * 16 + m) * 16 + wave * 4 + qd] = s2;
            SW[2048 + (tt * 16 + m) * 16 + wave * 4 + qd] = q2;
        }
        __syncthreads();
        if (t < 64) {
            float s2 = 0.f, q2 = 0.f;
#pragma unroll
            for (int i = 0; i < 16; ++i) { s2 += SW[t * 16 + i]; q2 += SW[2048 + t * 16 + i]; }
            int rep = (blockIdx.x & 3) * 128;
            atomicAdd(&stc[rep + t], s2);
            atomicAdd(&stc[rep + 64 + t], q2);
        }
        __threadfence();
        grid.sync();
        __threadfence();

        // BN finalize + apply + relu (+ residual) + write hbh
        finalize_lds(stc, ngm + mm * 64, nbt + mm * 64, SS, t, invN);
        __syncthreads();
#pragma unroll
        for (int s = 0; s < 2; ++s) {
            int grp = blockIdx.x + s * GNN_GRID;
            if (grp < NG) {
#pragma unroll
                for (int tt = 0; tt < 4; ++tt)
#pragma unroll
                    for (int r = 0; r < 4; ++r) {
                        int node = grp * 64 + wave * 16 + qd * 4 + r;
                        if (node < N) {
                            int col = tt * 16 + m;
                            float v = accg[s][tt][r];
                            v = fmaxf(v * SS[col] + SS[64 + col], 0.f);
                            if (cc) {
                                v += res[(size_t)node * 64 + col];
                                res[(size_t)node * 64 + col] = v;
                            }
                            unsigned short hb = f2bf(v);
                            hbh[(size_t)node * 64 + col] = hb;
                            if (conv == 7)
                                hbl[(size_t)node * 64 + col] = f2bf(v - bf2f(hb));
                        }
                    }
            }
        }
        __threadfence();
        grid.sync();
        __threadfence();
    }
}

// ---------------------------------------------------------------- fallback conv (r8 structure, walks 4 tile ranges)

__global__ void __launch_bounds__(256, 8)
k_conv_fb(const unsigned short* __restrict__ hbh,
          const int* __restrict__ rowptr4, const int* __restrict__ col4,
          const short* __restrict__ WH, const short* __restrict__ WL,
          const float* __restrict__ b3,
          float* __restrict__ z, float* __restrict__ stats, int N)
{
    __shared__ __align__(16) float Aint[64 * 68];
    __shared__ float BiasSh[192];
    int t = threadIdx.x;
    int wave = t >> 6, lane = t & 63;
    int m = lane & 15, qd = lane >> 4;
    int base = blockIdx.x * 64;
    float* Aw = Aint + wave * 1088;

    if (t < 192) BiasSh[t] = b3[t];

#pragma unroll 1
    for (int i = 0; i < 16; ++i) {
        int node = base + wave * 16 + i;
        float a = 0.f;
        if (node < N) {
            a = bf2f(hbh[(size_t)node * 64 + lane]);
#pragma unroll 1
            for (int tl = 0; tl < 4; ++tl) {
                int e0 = rowptr4[(size_t)tl * N + node];
                int e1 = rowptr4[(size_t)tl * N + node + 1];
                int e = e0;
                for (; e + 4 <= e1; e += 4) {
                    int s0 = col4[e + 0], s1 = col4[e + 1], s2 = col4[e + 2], s3 = col4[e + 3];
                    a += (bf2f(hbh[(size_t)s0 * 64 + lane]) + bf2f(hbh[(size_t)s1 * 64 + lane]))
                       + (bf2f(hbh[(size_t)s2 * 64 + lane]) + bf2f(hbh[(size_t)s3 * 64 + lane]));
                }
                for (; e < e1; ++e) a += bf2f(hbh[(size_t)col4[e] * 64 + lane]);
            }
        }
        Aw[i * 68 + lane] = a;
    }
    __syncthreads();

    floatx4 acc[4];
#pragma unroll 1
    for (int l = 0; l < 3; ++l) {
        const short* LH = WH + l * 4096;
        const short* LL = WL + l * 4096;
#pragma unroll
        for (int tt = 0; tt < 4; ++tt) {
            float bv = BiasSh[l * 64 + tt * 16 + m];
            acc[tt] = (floatx4){bv, bv, bv, bv};
        }
#pragma unroll
        for (int kc = 0; kc < 2; ++kc) {
            floatx4 x0 = *(const floatx4*)(Aw + m * 68 + kc * 32 + qd * 8);
            floatx4 x1 = *(const floatx4*)(Aw + m * 68 + kc * 32 + qd * 8 + 4);
            float av[8];
#pragma unroll
            for (int j = 0; j < 8; ++j) av[j] = (j < 4) ? x0[j] : x1[j - 4];
            bf16x8 ah, al;
            pack_pair(av, ah, al);
#pragma unroll
            for (int tt = 0; tt < 4; ++tt) {
                bf16x8 bh = BFRAG(LH, tt * 16 + m, kc, qd);
                bf16x8 bl = BFRAG(LL, tt * 16 + m, kc, qd);
                MFMA3(acc[tt], ah, al, bh, bl);
            }
        }
        if (l < 2) {
            __syncthreads();
#pragma unroll
            for (int tt = 0; tt < 4; ++tt)
#pragma unroll
                for (int r = 0; r < 4; ++r)
                    Aw[(qd * 4 + r) * 68 + tt * 16 + m] = fmaxf(acc[tt][r], 0.f);
            __syncthreads();
        }
    }

#pragma unroll
    for (int tt = 0; tt < 4; ++tt)
#pragma unroll
        for (int r = 0; r < 4; ++r) {
            int node = base + wave * 16 + qd * 4 + r;
            if (node < N)
                z[(size_t)node * 64 + tt * 16 + m] = acc[tt][r];
        }

    __syncthreads();
    float* SW = Aint;
#pragma unroll
    for (int tt = 0; tt < 4; ++tt) {
        float s = 0.f, q = 0.f;
#pragma unroll
        for (int r = 0; r < 4; ++r) {
            int node = base + wave * 16 + qd * 4 + r;
            float v = (node < N) ? acc[tt][r] : 0.f;
            s += v; q += v * v;
        }
        SW[(tt * 16 + m) * 16 + wave * 4 + qd] = s;
        SW[2048 + (tt * 16 + m) * 16 + wave * 4 + qd] = q;
    }
    __syncthreads();
    if (t < 64) {
        float s = 0.f, q = 0.f;
#pragma unroll
        for (int i = 0; i < 16; ++i) { s += SW[t * 16 + i]; q += SW[2048 + t * 16 + i]; }
        int rep = (blockIdx.x & 3) * 128;
        atomicAdd(&stats[rep + t], s);
        atomicAdd(&stats[rep + 64 + t], q);
    }
}

// ---------------------------------------------------------------- BN apply + relu (+ residual) — fallback path only

__global__ void k_bnrelu(const float4* __restrict__ z4,
                         const float* __restrict__ stats, const float* __restrict__ gamma,
                         const float* __restrict__ beta,
                         float4* __restrict__ res4,
                         ushort4* __restrict__ hbh4, ushort4* __restrict__ hbl4,
                         int second, int writeLo, int total4, float invN)
{
    __shared__ float SS[128];
    int t = threadIdx.x;
    finalize_lds(stats, gamma, beta, SS, t, invN);
    __syncthreads();
    for (int idx = blockIdx.x * 256 + t; idx < total4; idx += gridDim.x * 256) {
        int c = (idx & 15) << 2;
        float4 v = z4[idx];
        v.x = fmaxf(v.x * SS[c + 0] + SS[64 + c + 0], 0.f);
        v.y = fmaxf(v.y * SS[c + 1] + SS[64 + c + 1], 0.f);
        v.z = fmaxf(v.z * SS[c + 2] + SS[64 + c + 2], 0.f);
        v.w = fmaxf(v.w * SS[c + 3] + SS[64 + c + 3], 0.f);
        if (second) {
            float4 r = res4[idx];
            v.x += r.x; v.y += r.y; v.z += r.z; v.w += r.w;
            res4[idx] = v;
        }
        ushort4 ph;
        ph.x = f2bf(v.x); ph.y = f2bf(v.y); ph.z = f2bf(v.z); ph.w = f2bf(v.w);
        hbh4[idx] = ph;
        if (writeLo) {
            ushort4 pl;
            pl.x = f2bf(v.x - bf2f(ph.x));
            pl.y = f2bf(v.y - bf2f(ph.y));
            pl.z = f2bf(v.z - bf2f(ph.z));
            pl.w = f2bf(v.w - bf2f(ph.w));
            hbl4[idx] = pl;
        }
    }
}

// ---------------------------------------------------------------- attention readout

__global__ void __launch_bounds__(256, 4)
k_vs(const unsigned short* __restrict__ hbh, const unsigned short* __restrict__ hbl,
     const short* __restrict__ WH, const short* __restrict__ WL,
     const float* __restrict__ Wk, const float* __restrict__ seed,
     float* __restrict__ v, float* __restrict__ scores, int N)
{
    __shared__ short Sh[16 * 72], Sl[16 * 72];
    int t = threadIdx.x;
    int wave = t >> 6, lane = t & 63;
    int m = lane & 15, qd = lane >> 4;
    int base = blockIdx.x * 64;
    int nodeA = base + wave * 16 + m;

    {
        int k = t >> 2, n = t & 3;
        float s = 0.f;
#pragma unroll
        for (int d = 0; d < 16; ++d) s += Wk[k * 64 + n * 16 + d] * seed[n * 16 + d];
        s *= 0.25f;
        unsigned short hb = f2bf(s);
        Sh[n * 72 + k] = (short)hb;
        Sl[n * 72 + k] = (short)f2bf(s - bf2f(hb));
        unsigned int* Z1 = (unsigned int*)(Sh + 4 * 72);
        unsigned int* Z2 = (unsigned int*)(Sl + 4 * 72);
        for (int idx2 = t; idx2 < 432; idx2 += 256) { Z1[idx2] = 0; Z2[idx2] = 0; }
    }

    bf16x8 ah[2], al[2];
#pragma unroll
    for (int kc = 0; kc < 2; ++kc) {
        ah[kc] = *(const bf16x8*)(hbh + (size_t)nodeA * 64 + kc * 32 + qd * 8);
        al[kc] = *(const bf16x8*)(hbl + (size_t)nodeA * 64 + kc * 32 + qd * 8);
    }
    __syncthreads();

    floatx4 acc[5] = {};
#pragma unroll
    for (int kc = 0; kc < 2; ++kc) {
#pragma unroll
        for (int tt = 0; tt < 4; ++tt) {
            bf16x8 bh = BFRAG(WH, tt * 16 + m, kc, qd);
            bf16x8 bl = BFRAG(WL, tt * 16 + m, kc, qd);
            MFMA3(acc[tt], ah[kc], al[kc], bh, bl);
        }
        bf16x8 sh = *(const bf16x8*)(Sh + m * 72 + kc * 32 + qd * 8);
        bf16x8 sl = *(const bf16x8*)(Sl + m * 72 + kc * 32 + qd * 8);
        MFMA3(acc[4], ah[kc], al[kc], sh, sl);
    }

#pragma unroll
    for (int tt = 0; tt < 4; ++tt)
#pragma unroll
        for (int r = 0; r < 4; ++r) {
            int node = base + wave * 16 + qd * 4 + r;
            if (node < N)
                v[(size_t)node * 64 + tt * 16 + m] = acc[tt][r];
        }
    if (m < 4) {
#pragma unroll
        for (int r = 0; r < 4; ++r) {
            int node = base + wave * 16 + qd * 4 + r;
            if (node < N) scores[(size_t)node * 4 + m] = acc[4][r];
        }
    }
}

__global__ void k_pool(const float4* __restrict__ scores4, const float* __restrict__ v,
                       const int* __restrict__ batch, float* __restrict__ pooled, int N)
{
    int g = blockIdx.x;
    int t = threadIdx.x;
    __shared__ int sb[2];
    __shared__ float4 rmax[256];
    __shared__ float racc[256];
    __shared__ float resum[16];
    if (t < 2) {
        int target = g + t;
        int lo = 0, hi = N;
        while (lo < hi) {
            int mid = (lo + hi) >> 1;
            if (batch[mid] < target) lo = mid + 1; else hi = mid;
        }
        sb[t] = lo;
    }
    __syncthreads();
    int s = sb[0], e = sb[1];
    if (s >= e) {
        if (t < 64) pooled[g * 64 + t] = 0.f;
        return;
    }
    float4 m = make_float4(-1e30f, -1e30f, -1e30f, -1e30f);
    for (int i = s + t; i < e; i += 256) {
        float4 sc = scores4[i];
        m.x = fmaxf(m.x, sc.x); m.y = fmaxf(m.y, sc.y);
        m.z = fmaxf(m.z, sc.z); m.w = fmaxf(m.w, sc.w);
    }
    rmax[t] = m;
    __syncthreads();
    for (int off = 128; off; off >>= 1) {
        if (t < off) {
            float4 a = rmax[t], b = rmax[t + off];
            a.x = fmaxf(a.x, b.x); a.y = fmaxf(a.y, b.y);
            a.z = fmaxf(a.z, b.z); a.w = fmaxf(a.w, b.w);
            rmax[t] = a;
        }
        __syncthreads();
    }
    float4 smax = rmax[0];
    int rg = t >> 6, f = t & 63, hh = f >> 4;
    float mx = (hh == 0) ? smax.x : ((hh == 1) ? smax.y : ((hh == 2) ? smax.z : smax.w));
    float acc = 0.f, es = 0.f;
    for (int i = s + rg; i < e; i += 4) {
        float4 sc = scores4[i];
        float scl = (hh == 0) ? sc.x : ((hh == 1) ? sc.y : ((hh == 2) ? sc.z : sc.w));
        float ev = __expf(scl - mx);
        acc += ev * v[(size_t)i * 64 + f];
        if ((f & 15) == 0) es += ev;
    }
    racc[rg * 64 + f] = acc;
    if ((f & 15) == 0) resum[rg * 4 + hh] = es;
    __syncthreads();
    if (t < 64) {
        float tot = racc[t] + racc[64 + t] + racc[128 + t] + racc[192 + t];
        int h2 = t >> 4;
        float den = resum[h2] + resum[4 + h2] + resum[8 + h2] + resum[12 + h2];
        pooled[g * 64 + t] = tot / den;
    }
}

__global__ void k_embed(const float* __restrict__ pooled, const float* __restrict__ Wo,
                        float* __restrict__ out, int G)
{
    __shared__ __align__(16) float Ash[64 * LDA];
    __shared__ __align__(16) float Wsh[64 * 64];
    int t = threadIdx.x;
    int base = blockIdx.x * 64;
    stage_tile(pooled, base, G, Ash, t);
    stage_w(Wo, 64, Wsh, t);
    __syncthreads();
    int n0 = (t >> 4) << 2, f0 = (t & 15) << 2;
    float acc[4][4] = {};
    gemm_tile(Ash, Wsh, acc, n0, f0);
#pragma unroll
    for (int i = 0; i < 4; ++i) {
        int row = base + n0 + i;
        if (row < G)
            *(float4*)(out + (size_t)row * 64 + f0) =
                make_float4(acc[i][0], acc[i][1], acc[i][2], acc[i][3]);
    }
}

__global__ void k_logits(const float* __restrict__ embed, const float* __restrict__ W,
                         const float* __restrict__ b, float* __restrict__ out, int G)
{
    __shared__ __align__(16) float Ash[64 * LDA];
    __shared__ __align__(16) float Wsh[64 * 64];
    int t = threadIdx.x;
    int base = blockIdx.x * 64;
    int co = blockIdx.y * 64;
    stage_tile(embed, base, G, Ash, t);
#pragma unroll
    for (int i = 0; i < 4; ++i) {
        int idx = i * 256 + t;
        int k = idx >> 4;
        int f = (idx & 15) << 2;
        *(float4*)(Wsh + k * 64 + f) = *(const float4*)(W + (size_t)k * 128 + co + f);
    }
    __syncthreads();
    int n0 = (t >> 4) << 2, f0 = (t & 15) << 2;
    float acc[4][4];
    float4 b4 = *(const float4*)(b + co + f0);
#pragma unroll
    for (int i = 0; i < 4; ++i) { acc[i][0] = b4.x; acc[i][1] = b4.y; acc[i][2] = b4.z; acc[i][3] = b4.w; }
    gemm_tile(Ash, Wsh, acc, n0, f0);
#pragma unroll
    for (int i = 0; i < 4; ++i) {
        int row = base + n0 + i;
        if (row < G)
            *(float4*)(out + (size_t)row * 128 + co + f0) =
                make_float4(acc[i][0], acc[i][1], acc[i][2], acc[i][3]);
    }
}

// ---------------------------------------------------------------- launch

extern "C" void kernel_launch(void* const* d_in, const int* in_sizes, int n_in,
                              void* d_out, int out_size, void* d_ws, size_t ws_size,
                              hipStream_t stream)
{
    const float* x     = (const float*)d_in[0];
    const int*   eidx  = (const int*)d_in[1];
    const int*   batch = (const int*)d_in[2];
    const float* fn_g  = (const float*)d_in[3];
    const float* fn_b  = (const float*)d_in[4];
    const float* pW    = (const float*)d_in[5];
    const float* pb    = (const float*)d_in[6];
    const float* mlpW  = (const float*)d_in[7];
    const float* mlpb  = (const float*)d_in[8];
    const float* ngm   = (const float*)d_in[9];
    const float* nbt   = (const float*)d_in[10];
    const float* seed  = (const float*)d_in[11];
    const float* Wk    = (const float*)d_in[12];
    const float* Wv    = (const float*)d_in[13];
    const float* Wo    = (const float*)d_in[14];
    const float* predW = (const float*)d_in[15];
    const float* predb = (const float*)d_in[16];

    const int N = 100000, E = 1000000, G = 1000;
    const int* srcv = eidx;
    const int* dstv = eidx + E;

    char* w = (char*)d_ws;
    auto alloc = [&](size_t bytes) {
        char* p = w;
        w += (bytes + 255) & ~(size_t)255;
        return p;
    };
    const size_t NPAD = 100032;  // 1563 * 64
    float*          res  = (float*)alloc(NPAD * 64 * 4);
    float*          vbuf = (float*)alloc(NPAD * 64 * 4);   // v in readout; z in fallback path
    unsigned short* hbh  = (unsigned short*)alloc(NPAD * 64 * 2);
    unsigned short* hbl  = (unsigned short*)alloc(NPAD * 64 * 2);
    short* preH = (short*)alloc(14 * 4096 * 2);
    short* preL = (short*)alloc(14 * 4096 * 2);
    int*   rowptr4 = (int*)alloc(((size_t)4 * N + 4) * 4);
    int*   cnt4    = (int*)alloc((size_t)4 * N * 4);
    int*   col4    = (int*)alloc((size_t)E * 4);
    int*   bsum   = (int*)alloc(512 * 4);
    int*   boff   = (int*)alloc(512 * 4);
    float* stats  = (float*)alloc(9 * 512 * 4);
    float* scores = (float*)alloc(NPAD * 4 * 4);
    float* pooled = (float*)alloc((size_t)G * 64 * 4);

    float* emb    = (float*)d_out;            // [G,64]
    float* logits = (float*)d_out + G * 64;   // [G,128]

    const int NB = (N + 63) / 64;       // 1563
    const int N4 = N;                   // int4 groups over cnt4 (4N ints)
    const int NBS4 = (N4 + 255) / 256;  // 391
    const float invN = 1.f / (float)N;

    // weight prep + tile-partitioned CSR build
    hipMemsetAsync(cnt4, 0, (size_t)4 * N * 4, stream);
    hipMemsetAsync(stats, 0, 9 * 512 * 4, stream);
    k_prep<<<14, 256, 0, stream>>>(pW, mlpW, Wv, preH, preL);
    k_count4<<<1024, 256, 0, stream>>>(srcv, dstv, cnt4, E, N);
    k_scan1b<<<NBS4, 256, 0, stream>>>(cnt4, bsum, N4);
    k_scan2<<<1, 512, 0, stream>>>(bsum, boff, NBS4, rowptr4 + 4 * N);
    k_scan3b<<<NBS4, 256, 0, stream>>>(cnt4, boff, rowptr4, N4);
    k_fill4<<<1024, 256, 0, stream>>>(srcv, dstv, rowptr4, cnt4, col4, E, N);

    // feature BN + projection
    k_xstats<<<512, 256, 0, stream>>>(x, stats, N);
    k_proj<<<NB, 256, 0, stream>>>(x, stats, fn_g, fn_b, preH, preL, pb, res, hbh, N, invN);

    // GIN stack: cooperative if capacity allows (gated by deterministic occupancy query)
    int occ = 0;
    hipOccupancyMaxActiveBlocksPerMultiprocessor(&occ, k_gnn, 256, 0);
    bool coop = ((long)occ * 256 >= GNN_GRID);
    if (coop) {
        int Nv = N;
        float invNv = invN;
        void* args[] = { (void*)&hbh, (void*)&hbl, (void*)&rowptr4, (void*)&col4,
                         (void*)&preH, (void*)&preL, (void*)&mlpb, (void*)&ngm,
                         (void*)&nbt, (void*)&res, (void*)&stats, (void*)&Nv, (void*)&invNv };
        hipError_t err = hipLaunchCooperativeKernel((const void*)k_gnn, dim3(GNN_GRID),
                                                    dim3(256), args, 0, stream);
        if (err != hipSuccess) coop = false;
    }
    if (!coop) {
        float* z = vbuf;
        for (int m = 0; m < 4; ++m)
            for (int c = 0; c < 2; ++c) {
                int sidx = 1 + m * 2 + c;
                int mat = 1 + m * 3;
                k_conv_fb<<<NB, 256, 0, stream>>>(hbh, rowptr4, col4,
                                                  preH + (size_t)mat * 4096,
                                                  preL + (size_t)mat * 4096,
                                                  mlpb + (size_t)m * 3 * 64,
                                                  z, stats + (size_t)sidx * 512, N);
                int last = (m == 3 && c == 1) ? 1 : 0;
                k_bnrelu<<<2048, 256, 0, stream>>>(
                    (const float4*)z,
                    stats + (size_t)sidx * 512, ngm + m * 64, nbt + m * 64,
                    (float4*)res, (ushort4*)hbh, (ushort4*)hbl,
                    (c == 1) ? 1 : 0, last, N * 16, invN);
            }
    }

    // attention readout
    k_vs<<<NB, 256, 0, stream>>>(hbh, hbl, preH + 13 * 4096, preL + 13 * 4096,
                                 Wk, seed, vbuf, scores, N);
    k_pool<<<G, 256, 0, stream>>>((const float4*)scores, vbuf, batch, pooled, N);
    k_embed<<<(G + 63) / 64, 256, 0, stream>>>(pooled, Wo, emb, G);
    dim3 lg((G + 63) / 64, 2);
    k_logits<<<lg, 256, 0, stream>>>(emb, predW, predb, logits, G);
}

// Round 11
// 1007.010 us; speedup vs baseline: 1.5714x; 1.5714x over previous
//
#include <hip/hip_runtime.h>

#define LDA 68  // padded leading dim for 64-wide fp32 LDS tiles

typedef __attribute__((ext_vector_type(8))) short bf16x8;
typedef __attribute__((ext_vector_type(4))) float floatx4;

// bf16 helpers (RNE)
__device__ __forceinline__ unsigned short f2bf(float f)
{
    union { float f; unsigned int u; } v; v.f = f;
    unsigned int r = (v.u + 0x7fffu + ((v.u >> 16) & 1u)) >> 16;
    return (unsigned short)r;
}
__device__ __forceinline__ float bf2f(unsigned short b)
{
    union { unsigned int u; float f; } v; v.u = ((unsigned int)b) << 16;
    return v.f;
}

// acc += (Ah+Al) * (Bh+Bl), dropping Al*Bl  (~16-bit-mantissa GEMM)
#define MFMA3(accv, ah, al, bh, bl)                                              \
    accv = __builtin_amdgcn_mfma_f32_16x16x32_bf16(ah, bh, accv, 0, 0, 0);       \
    accv = __builtin_amdgcn_mfma_f32_16x16x32_bf16(al, bh, accv, 0, 0, 0);       \
    accv = __builtin_amdgcn_mfma_f32_16x16x32_bf16(ah, bl, accv, 0, 0, 0);

// B-fragment read from prepped global weights ([n][64k] shorts, 16B aligned)
#define BFRAG(P, n, kc, qd) (*(const bf16x8*)((P) + ((n) << 6) + (kc) * 32 + (qd) * 8))

__device__ __forceinline__ void pack_pair(const float* f, bf16x8& hi, bf16x8& lo)
{
#pragma unroll
    for (int j = 0; j < 8; ++j) {
        unsigned short hb = f2bf(f[j]);
        hi[j] = (short)hb;
        lo[j] = (short)f2bf(f[j] - bf2f(hb));
    }
}

// ---------------------------------------------------------------- weight prep (once per launch)
// mats: 0 = proj_W, 1..12 = mlp_W[m*3+l], 13 = Wv.

__global__ void k_prep(const float* __restrict__ pW, const float* __restrict__ mlpW,
                       const float* __restrict__ Wv,
                       short* __restrict__ preH, short* __restrict__ preL)
{
    int mat = blockIdx.x;
    const float* Wg = (mat == 0) ? pW : ((mat <= 12) ? mlpW + (size_t)(mat - 1) * 4096 : Wv);
    int t = threadIdx.x;
    short* dh = preH + (size_t)mat * 4096;
    short* dl = preL + (size_t)mat * 4096;
#pragma unroll
    for (int i = 0; i < 16; ++i) {
        int idx = i * 256 + t;
        int k = idx >> 6, n = idx & 63;
        float w = Wg[idx];  // idx = k*64+n, coalesced
        unsigned short hb = f2bf(w);
        dh[n * 64 + k] = (short)hb;
        dl[n * 64 + k] = (short)f2bf(w - bf2f(hb));
    }
}

// ---------------------------------------------------------------- CSR build

__global__ void k_count(const int* __restrict__ dst, int* __restrict__ cnt, int E)
{
    for (int e = blockIdx.x * 256 + threadIdx.x; e < E; e += gridDim.x * 256)
        atomicAdd(&cnt[dst[e]], 1);
}

__global__ void k_scan1(const int* __restrict__ cnt, int* __restrict__ bsum, int n)
{
    __shared__ int red[256];
    int t = threadIdx.x;
    int i = blockIdx.x * 256 + t;
    red[t] = (i < n) ? cnt[i] : 0;
    __syncthreads();
    for (int off = 128; off; off >>= 1) {
        if (t < off) red[t] += red[t + off];
        __syncthreads();
    }
    if (t == 0) bsum[blockIdx.x] = red[0];
}

__global__ void k_scan2(const int* __restrict__ bsum, int* __restrict__ boff,
                        int nb, int* __restrict__ rowptrN)
{
    __shared__ int sc[512];
    int t = threadIdx.x;
    int v = (t < nb) ? bsum[t] : 0;
    sc[t] = v;
    __syncthreads();
    for (int off = 1; off < 512; off <<= 1) {
        int u = (t >= off) ? sc[t - off] : 0;
        __syncthreads();
        sc[t] += u;
        __syncthreads();
    }
    if (t < nb) boff[t] = sc[t] - v;
    if (t == nb - 1) *rowptrN = sc[t];
}

// also re-zeros cnt so k_fill can use it as cursor without a memset
__global__ void k_scan3(int* __restrict__ cnt, const int* __restrict__ boff,
                        int* __restrict__ rowptr, int n)
{
    __shared__ int sc[256];
    int t = threadIdx.x;
    int i = blockIdx.x * 256 + t;
    int v = (i < n) ? cnt[i] : 0;
    sc[t] = v;
    __syncthreads();
    for (int off = 1; off < 256; off <<= 1) {
        int u = (t >= off) ? sc[t - off] : 0;
        __syncthreads();
        sc[t] += u;
        __syncthreads();
    }
    if (i < n) {
        rowptr[i] = boff[blockIdx.x] + sc[t] - v;
        cnt[i] = 0;
    }
}

__global__ void k_fill(const int* __restrict__ src, const int* __restrict__ dst,
                       const int* __restrict__ rowptr, int* __restrict__ cursor,
                       int* __restrict__ col, int E)
{
    for (int e = blockIdx.x * 256 + threadIdx.x; e < E; e += gridDim.x * 256) {
        int d = dst[e];
        int p = atomicAdd(&cursor[d], 1);
        col[rowptr[d] + p] = src[e];
    }
}

// ---------------------------------------------------------------- feature BN stats (4-way replicated atomics)

__global__ void k_xstats(const float* __restrict__ x, float* __restrict__ stats, int N)
{
    __shared__ float rs[256], rq[256];
    int t = threadIdx.x;
    int f = t & 63, rg = t >> 6;
    float s = 0.f, q = 0.f;
    for (int r = blockIdx.x * 4 + rg; r < N; r += gridDim.x * 4) {
        float v = x[(size_t)r * 64 + f];
        s += v; q += v * v;
    }
    rs[rg * 64 + f] = s; rq[rg * 64 + f] = q;
    __syncthreads();
    if (t < 64) {
        float ts = rs[t] + rs[64 + t] + rs[128 + t] + rs[192 + t];
        float tq = rq[t] + rq[64 + t] + rq[128 + t] + rq[192 + t];
        int rep = (blockIdx.x & 3) * 128;
        atomicAdd(&stats[rep + t], ts);
        atomicAdd(&stats[rep + 64 + t], tq);
    }
}

// compute per-feature scale/shift from 4-replica stats into LDS[128]
__device__ __forceinline__ void finalize_lds(const float* __restrict__ stats,
                                             const float* __restrict__ gamma,
                                             const float* __restrict__ beta,
                                             float* __restrict__ SS, int t, float invN)
{
    if (t < 64) {
        float su = stats[t] + stats[128 + t] + stats[256 + t] + stats[384 + t];
        float qu = stats[64 + t] + stats[192 + t] + stats[320 + t] + stats[448 + t];
        float mu = su * invN;
        float var = qu * invN - mu * mu;
        float sc = gamma[t] * rsqrtf(var + 1e-5f);
        SS[t] = sc;
        SS[64 + t] = beta[t] - mu * sc;
    }
}

// ---------------------------------------------------------------- input projection (MFMA, weights from prepped global)

__global__ void __launch_bounds__(256, 4)
k_proj(const float* __restrict__ x, const float* __restrict__ stats,
       const float* __restrict__ fn_g, const float* __restrict__ fn_b,
       const short* __restrict__ WH, const short* __restrict__ WL,
       const float* __restrict__ b,
       float* __restrict__ res, unsigned short* __restrict__ hbh,
       int N, float invN)
{
    __shared__ float ScSh[128];
    __shared__ float BiasSh[64];
    int t = threadIdx.x;
    int wave = t >> 6, lane = t & 63;
    int m = lane & 15, qd = lane >> 4;
    int base = blockIdx.x * 64;
    int nodeA = base + wave * 16 + m;

    finalize_lds(stats, fn_g, fn_b, ScSh, t, invN);
    if (t < 64) BiasSh[t] = b[t];
    __syncthreads();

    int rowc = min(nodeA, N - 1);
    bf16x8 ah[2], al[2];
#pragma unroll
    for (int kc = 0; kc < 2; ++kc) {
        floatx4 x0 = *(const floatx4*)(x + (size_t)rowc * 64 + kc * 32 + qd * 8);
        floatx4 x1 = *(const floatx4*)(x + (size_t)rowc * 64 + kc * 32 + qd * 8 + 4);
        float av[8];
#pragma unroll
        for (int j = 0; j < 8; ++j) {
            int k = kc * 32 + qd * 8 + j;
            float xv = (j < 4) ? x0[j] : x1[j - 4];
            av[j] = xv * ScSh[k] + ScSh[64 + k];
        }
        pack_pair(av, ah[kc], al[kc]);
    }

    floatx4 acc[4];
#pragma unroll
    for (int tt = 0; tt < 4; ++tt) {
        float bv = BiasSh[tt * 16 + m];
        acc[tt] = (floatx4){bv, bv, bv, bv};
    }
#pragma unroll
    for (int kc = 0; kc < 2; ++kc)
#pragma unroll
        for (int tt = 0; tt < 4; ++tt) {
            bf16x8 bh = BFRAG(WH, tt * 16 + m, kc, qd);
            bf16x8 bl = BFRAG(WL, tt * 16 + m, kc, qd);
            MFMA3(acc[tt], ah[kc], al[kc], bh, bl);
        }

#pragma unroll
    for (int tt = 0; tt < 4; ++tt)
#pragma unroll
        for (int r = 0; r < 4; ++r) {
            int node = base + wave * 16 + qd * 4 + r;
            if (node < N) {
                int col = tt * 16 + m;
                float v = fmaxf(acc[tt][r], 0.f);
                res[(size_t)node * 64 + col] = v;
                hbh[(size_t)node * 64 + col] = f2bf(v);
            }
        }
}

// ---------------------------------------------------------------- fused GIN conv: gather + 3-layer MFMA MLP + BN stats
// Gather is at the fabric transaction wall (~25 G cachelines/s: 2 lines/edge,
// measured concurrency-insensitive r2/r8) — LDS kept minimal for 8 blocks/CU.

__global__ void __launch_bounds__(256, 8)
k_conv(const unsigned short* __restrict__ hbh,
       const int* __restrict__ rowptr, const int* __restrict__ col,
       const short* __restrict__ WH, const short* __restrict__ WL,
       const float* __restrict__ b3,
       float* __restrict__ z, float* __restrict__ stats, int N)
{
    __shared__ __align__(16) float Aint[64 * 68];
    __shared__ float BiasSh[192];
    int t = threadIdx.x;
    int wave = t >> 6, lane = t & 63;
    int m = lane & 15, qd = lane >> 4;
    int base = blockIdx.x * 64;
    float* Aw = Aint + wave * 1088;  // private 16 rows x 68

    if (t < 192) BiasSh[t] = b3[t];

    // ---- gather: self + neighbors, all bf16 (lane = feature)
#pragma unroll 1
    for (int i = 0; i < 16; ++i) {
        int node = base + wave * 16 + i;
        float a = 0.f;
        if (node < N) {
            a = bf2f(hbh[(size_t)node * 64 + lane]);
            int e0 = rowptr[node], e1 = rowptr[node + 1];
            int e = e0;
            for (; e + 8 <= e1; e += 8) {
                int s0 = col[e + 0], s1 = col[e + 1], s2 = col[e + 2], s3 = col[e + 3];
                int s4 = col[e + 4], s5 = col[e + 5], s6 = col[e + 6], s7 = col[e + 7];
                float v0 = bf2f(hbh[(size_t)s0 * 64 + lane]);
                float v1 = bf2f(hbh[(size_t)s1 * 64 + lane]);
                float v2 = bf2f(hbh[(size_t)s2 * 64 + lane]);
                float v3 = bf2f(hbh[(size_t)s3 * 64 + lane]);
                float v4 = bf2f(hbh[(size_t)s4 * 64 + lane]);
                float v5 = bf2f(hbh[(size_t)s5 * 64 + lane]);
                float v6 = bf2f(hbh[(size_t)s6 * 64 + lane]);
                float v7 = bf2f(hbh[(size_t)s7 * 64 + lane]);
                a += ((v0 + v1) + (v2 + v3)) + ((v4 + v5) + (v6 + v7));
            }
            if (e + 4 <= e1) {
                int s0 = col[e + 0], s1 = col[e + 1], s2 = col[e + 2], s3 = col[e + 3];
                a += (bf2f(hbh[(size_t)s0 * 64 + lane]) + bf2f(hbh[(size_t)s1 * 64 + lane]))
                   + (bf2f(hbh[(size_t)s2 * 64 + lane]) + bf2f(hbh[(size_t)s3 * 64 + lane]));
                e += 4;
            }
            if (e + 2 <= e1) {
                a += bf2f(hbh[(size_t)col[e] * 64 + lane]) + bf2f(hbh[(size_t)col[e + 1] * 64 + lane]);
                e += 2;
            }
            if (e < e1) a += bf2f(hbh[(size_t)col[e] * 64 + lane]);
        }
        Aw[i * 68 + lane] = a;
    }
    __syncthreads();

    floatx4 acc[4];

#pragma unroll 1
    for (int l = 0; l < 3; ++l) {
        const short* LH = WH + l * 4096;
        const short* LL = WL + l * 4096;
#pragma unroll
        for (int tt = 0; tt < 4; ++tt) {
            float bv = BiasSh[l * 64 + tt * 16 + m];
            acc[tt] = (floatx4){bv, bv, bv, bv};
        }
#pragma unroll
        for (int kc = 0; kc < 2; ++kc) {
            floatx4 x0 = *(const floatx4*)(Aw + m * 68 + kc * 32 + qd * 8);
            floatx4 x1 = *(const floatx4*)(Aw + m * 68 + kc * 32 + qd * 8 + 4);
            float av[8];
#pragma unroll
            for (int j = 0; j < 8; ++j) av[j] = (j < 4) ? x0[j] : x1[j - 4];
            bf16x8 ah, al;
            pack_pair(av, ah, al);
#pragma unroll
            for (int tt = 0; tt < 4; ++tt) {
                bf16x8 bh = BFRAG(LH, tt * 16 + m, kc, qd);
                bf16x8 bl = BFRAG(LL, tt * 16 + m, kc, qd);
                MFMA3(acc[tt], ah, al, bh, bl);
            }
        }
        if (l < 2) {
            __syncthreads();  // Aw reads (all waves' lanes) done before overwrite
#pragma unroll
            for (int tt = 0; tt < 4; ++tt)
#pragma unroll
                for (int r = 0; r < 4; ++r)
                    Aw[(qd * 4 + r) * 68 + tt * 16 + m] = fmaxf(acc[tt][r], 0.f);
            __syncthreads();
        }
    }

    // store pre-BN z (fp32, exact)
#pragma unroll
    for (int tt = 0; tt < 4; ++tt)
#pragma unroll
        for (int r = 0; r < 4; ++r) {
            int node = base + wave * 16 + qd * 4 + r;
            if (node < N)
                z[(size_t)node * 64 + tt * 16 + m] = acc[tt][r];
        }

    // BN partial stats from fp32 accumulators (Aint reused as scratch)
    __syncthreads();
    float* SW = Aint;
#pragma unroll
    for (int tt = 0; tt < 4; ++tt) {
        float s = 0.f, q = 0.f;
#pragma unroll
        for (int r = 0; r < 4; ++r) {
            int node = base + wave * 16 + qd * 4 + r;
            float v = (node < N) ? acc[tt][r] : 0.f;
            s += v; q += v * v;
        }
        SW[(tt * 16 + m) * 16 + wave * 4 + qd] = s;
        SW[2048 + (tt * 16 + m) * 16 + wave * 4 + qd] = q;
    }
    __syncthreads();
    if (t < 64) {
        float s = 0.f, q = 0.f;
#pragma unroll
        for (int i = 0; i < 16; ++i) { s += SW[t * 16 + i]; q += SW[2048 + t * 16 + i]; }
        int rep = (blockIdx.x & 3) * 128;
        atomicAdd(&stats[rep + t], s);
        atomicAdd(&stats[rep + 64 + t], q);
    }
}

// ---------------------------------------------------------------- BN apply + relu (+ residual), inline finalize

__global__ void k_bnrelu(const float4* __restrict__ z4,
                         const float* __restrict__ stats, const float* __restrict__ gamma,
                         const float* __restrict__ beta,
                         float4* __restrict__ res4,
                         ushort4* __restrict__ hbh4, ushort4* __restrict__ hbl4,
                         int second, int writeLo, int total4, float invN)
{
    __shared__ float SS[128];
    int t = threadIdx.x;
    finalize_lds(stats, gamma, beta, SS, t, invN);
    __syncthreads();
    for (int idx = blockIdx.x * 256 + t; idx < total4; idx += gridDim.x * 256) {
        int c = (idx & 15) << 2;
        float4 v = z4[idx];
        v.x = fmaxf(v.x * SS[c + 0] + SS[64 + c + 0], 0.f);
        v.y = fmaxf(v.y * SS[c + 1] + SS[64 + c + 1], 0.f);
        v.z = fmaxf(v.z * SS[c + 2] + SS[64 + c + 2], 0.f);
        v.w = fmaxf(v.w * SS[c + 3] + SS[64 + c + 3], 0.f);
        if (second) {
            float4 r = res4[idx];
            v.x += r.x; v.y += r.y; v.z += r.z; v.w += r.w;
            res4[idx] = v;
        }
        ushort4 ph;
        ph.x = f2bf(v.x); ph.y = f2bf(v.y); ph.z = f2bf(v.z); ph.w = f2bf(v.w);
        hbh4[idx] = ph;
        if (writeLo) {
            ushort4 pl;
            pl.x = f2bf(v.x - bf2f(ph.x));
            pl.y = f2bf(v.y - bf2f(ph.y));
            pl.z = f2bf(v.z - bf2f(ph.z));
            pl.w = f2bf(v.w - bf2f(ph.w));
            hbl4[idx] = pl;
        }
    }
}

// ---------------------------------------------------------------- attention readout
// v = h @ Wv (MFMA, Wv from prepped global) and scores = h @ (Wk @ seed / 4).

__global__ void __launch_bounds__(256, 4)
k_vs(const unsigned short* __restrict__ hbh, const unsigned short* __restrict__ hbl,
     const short* __restrict__ WH, const short* __restrict__ WL,
     const float* __restrict__ Wk, const float* __restrict__ seed,
     float* __restrict__ v, float* __restrict__ scores, int N)
{
    __shared__ short Sh[16 * 72], Sl[16 * 72];
    int t = threadIdx.x;
    int wave = t >> 6, lane = t & 63;
    int m = lane & 15, qd = lane >> 4;
    int base = blockIdx.x * 64;
    int nodeA = base + wave * 16 + m;

    {   // inline wks: element (k = t>>2, head n = t&3); rows 4..15 zeroed
        int k = t >> 2, n = t & 3;
        float s = 0.f;
#pragma unroll
        for (int d = 0; d < 16; ++d) s += Wk[k * 64 + n * 16 + d] * seed[n * 16 + d];
        s *= 0.25f;  // 1/sqrt(16)
        unsigned short hb = f2bf(s);
        Sh[n * 72 + k] = (short)hb;
        Sl[n * 72 + k] = (short)f2bf(s - bf2f(hb));
        unsigned int* Z1 = (unsigned int*)(Sh + 4 * 72);
        unsigned int* Z2 = (unsigned int*)(Sl + 4 * 72);
        for (int idx2 = t; idx2 < 432; idx2 += 256) { Z1[idx2] = 0; Z2[idx2] = 0; }
    }

    bf16x8 ah[2], al[2];
#pragma unroll
    for (int kc = 0; kc < 2; ++kc) {
        ah[kc] = *(const bf16x8*)(hbh + (size_t)nodeA * 64 + kc * 32 + qd * 8);
        al[kc] = *(const bf16x8*)(hbl + (size_t)nodeA * 64 + kc * 32 + qd * 8);
    }
    __syncthreads();

    floatx4 acc[5] = {};
#pragma unroll
    for (int kc = 0; kc < 2; ++kc) {
#pragma unroll
        for (int tt = 0; tt < 4; ++tt) {
            bf16x8 bh = BFRAG(WH, tt * 16 + m, kc, qd);
            bf16x8 bl = BFRAG(WL, tt * 16 + m, kc, qd);
            MFMA3(acc[tt], ah[kc], al[kc], bh, bl);
        }
        bf16x8 sh = *(const bf16x8*)(Sh + m * 72 + kc * 32 + qd * 8);
        bf16x8 sl = *(const bf16x8*)(Sl + m * 72 + kc * 32 + qd * 8);
        MFMA3(acc[4], ah[kc], al[kc], sh, sl);
    }

#pragma unroll
    for (int tt = 0; tt < 4; ++tt)
#pragma unroll
        for (int r = 0; r < 4; ++r) {
            int node = base + wave * 16 + qd * 4 + r;
            if (node < N)
                v[(size_t)node * 64 + tt * 16 + m] = acc[tt][r];
        }
    if (m < 4) {
#pragma unroll
        for (int r = 0; r < 4; ++r) {
            int node = base + wave * 16 + qd * 4 + r;
            if (node < N) scores[(size_t)node * 4 + m] = acc[4][r];
        }
    }
}

// ---------------------------------------------------------------- fused tail: softmax pool + embed + logits
// One block per graph: pool into LDS, then embed row (64x64 matvec) and
// logits row (64x128) computed in-block. Wo/predW stay L2-hot across 1000 blocks.

__global__ void k_tail(const float4* __restrict__ scores4, const float* __restrict__ v,
                       const int* __restrict__ batch,
                       const float* __restrict__ Wo, const float* __restrict__ predW,
                       const float* __restrict__ predb,
                       float* __restrict__ emb, float* __restrict__ logits, int N)
{
    int g = blockIdx.x;
    int t = threadIdx.x;
    __shared__ int sb[2];
    __shared__ float4 rmax[256];
    __shared__ float racc[256];
    __shared__ float resum[16];
    __shared__ float pooledSh[64];
    __shared__ float embSh[64];
    if (t < 2) {
        int target = g + t;
        int lo = 0, hi = N;
        while (lo < hi) {
            int mid = (lo + hi) >> 1;
            if (batch[mid] < target) lo = mid + 1; else hi = mid;
        }
        sb[t] = lo;
    }
    __syncthreads();
    int s = sb[0], e = sb[1];
    if (s >= e) {
        if (t < 64) pooledSh[t] = 0.f;  // empty graph: pooled = 0 -> logits = bias
    } else {
        float4 m = make_float4(-1e30f, -1e30f, -1e30f, -1e30f);
        for (int i = s + t; i < e; i += 256) {
            float4 sc = scores4[i];
            m.x = fmaxf(m.x, sc.x); m.y = fmaxf(m.y, sc.y);
            m.z = fmaxf(m.z, sc.z); m.w = fmaxf(m.w, sc.w);
        }
        rmax[t] = m;
        __syncthreads();
        for (int off = 128; off; off >>= 1) {
            if (t < off) {
                float4 a = rmax[t], b = rmax[t + off];
                a.x = fmaxf(a.x, b.x); a.y = fmaxf(a.y, b.y);
                a.z = fmaxf(a.z, b.z); a.w = fmaxf(a.w, b.w);
                rmax[t] = a;
            }
            __syncthreads();
        }
        float4 smax = rmax[0];
        int rg = t >> 6, f = t & 63, hh = f >> 4;
        float mx = (hh == 0) ? smax.x : ((hh == 1) ? smax.y : ((hh == 2) ? smax.z : smax.w));
        float acc = 0.f, es = 0.f;
        for (int i = s + rg; i < e; i += 4) {
            float4 sc = scores4[i];
            float scl = (hh == 0) ? sc.x : ((hh == 1) ? sc.y : ((hh == 2) ? sc.z : sc.w));
            float ev = __expf(scl - mx);
            acc += ev * v[(size_t)i * 64 + f];
            if ((f & 15) == 0) es += ev;
        }
        racc[rg * 64 + f] = acc;
        if ((f & 15) == 0) resum[rg * 4 + hh] = es;
        __syncthreads();
        if (t < 64) {
            float tot = racc[t] + racc[64 + t] + racc[128 + t] + racc[192 + t];
            int h2 = t >> 4;
            float den = resum[h2] + resum[4 + h2] + resum[8 + h2] + resum[12 + h2];
            pooledSh[t] = tot / den;
        }
    }
    __syncthreads();

    // embed row: emb[g][t] = sum_k pooled[k] * Wo[k][t]   (t coalesced over Wo rows)
    if (t < 64) {
        float s2 = 0.f;
#pragma unroll 4
        for (int k = 0; k < 64; ++k) s2 = fmaf(pooledSh[k], Wo[k * 64 + t], s2);
        embSh[t] = s2;
        emb[(size_t)g * 64 + t] = s2;
    }
    __syncthreads();

    // logits row: logits[g][t] = predb[t] + sum_k emb[k] * predW[k][t]
    if (t < 128) {
        float s2 = predb[t];
#pragma unroll 4
        for (int k = 0; k < 64; ++k) s2 = fmaf(embSh[k], predW[k * 128 + t], s2);
        logits[(size_t)g * 128 + t] = s2;
    }
}

// ---------------------------------------------------------------- launch

extern "C" void kernel_launch(void* const* d_in, const int* in_sizes, int n_in,
                              void* d_out, int out_size, void* d_ws, size_t ws_size,
                              hipStream_t stream)
{
    const float* x     = (const float*)d_in[0];
    const int*   eidx  = (const int*)d_in[1];
    const int*   batch = (const int*)d_in[2];
    const float* fn_g  = (const float*)d_in[3];
    const float* fn_b  = (const float*)d_in[4];
    const float* pW    = (const float*)d_in[5];
    const float* pb    = (const float*)d_in[6];
    const float* mlpW  = (const float*)d_in[7];
    const float* mlpb  = (const float*)d_in[8];
    const float* ngm   = (const float*)d_in[9];
    const float* nbt   = (const float*)d_in[10];
    const float* seed  = (const float*)d_in[11];
    const float* Wk    = (const float*)d_in[12];
    const float* Wv    = (const float*)d_in[13];
    const float* Wo    = (const float*)d_in[14];
    const float* predW = (const float*)d_in[15];
    const float* predb = (const float*)d_in[16];

    const int N = 100000, E = 1000000, G = 1000;
    const int* srcv = eidx;
    const int* dstv = eidx + E;

    char* w = (char*)d_ws;
    auto alloc = [&](size_t bytes) {
        char* p = w;
        w += (bytes + 255) & ~(size_t)255;
        return p;
    };
    const size_t NPAD = 100032;  // 1563 * 64
    float*          res  = (float*)alloc(NPAD * 64 * 4);   // residual; reused as v in readout
    float*          z    = (float*)alloc(NPAD * 64 * 4);   // pre-BN conv output (fp32)
    unsigned short* hbh  = (unsigned short*)alloc(NPAD * 64 * 2);  // h bf16 hi
    unsigned short* hbl  = (unsigned short*)alloc(NPAD * 64 * 2);  // h bf16 lo (written before readout only)
    short* preH = (short*)alloc(14 * 4096 * 2);  // prepped weights bf16 hi, [mat][n][k]
    short* preL = (short*)alloc(14 * 4096 * 2);  // prepped weights bf16 lo
    int*   rowptr = (int*)alloc((size_t)(N + 1) * 4);
    int*   cnt    = (int*)alloc((size_t)N * 4);
    int*   col    = (int*)alloc((size_t)E * 4);
    int*   bsum   = (int*)alloc(512 * 4);
    int*   boff   = (int*)alloc(512 * 4);
    float* stats  = (float*)alloc(9 * 512 * 4);   // 4 replicas x 128 per stage
    float* scores = (float*)alloc(NPAD * 4 * 4);

    float* emb    = (float*)d_out;            // [G,64]
    float* logits = (float*)d_out + G * 64;   // [G,128]

    const int NB = (N + 63) / 64;     // 1563
    const int NBS = (N + 255) / 256;  // 391
    const float invN = 1.f / (float)N;

    // weight prep (once) + CSR build
    hipMemsetAsync(cnt, 0, (size_t)N * 4, stream);
    hipMemsetAsync(stats, 0, 9 * 512 * 4, stream);
    k_prep<<<14, 256, 0, stream>>>(pW, mlpW, Wv, preH, preL);
    k_count<<<1024, 256, 0, stream>>>(dstv, cnt, E);
    k_scan1<<<NBS, 256, 0, stream>>>(cnt, bsum, N);
    k_scan2<<<1, 512, 0, stream>>>(bsum, boff, NBS, rowptr + N);
    k_scan3<<<NBS, 256, 0, stream>>>(cnt, boff, rowptr, N);
    k_fill<<<1024, 256, 0, stream>>>(srcv, dstv, rowptr, cnt, col, E);

    // feature BN + projection
    k_xstats<<<512, 256, 0, stream>>>(x, stats, N);
    k_proj<<<NB, 256, 0, stream>>>(x, stats, fn_g, fn_b, preH, preL, pb, res, hbh, N, invN);

    // 4 MPNN blocks x 2 GIN convs
    for (int m = 0; m < 4; ++m)
        for (int c = 0; c < 2; ++c) {
            int sidx = 1 + m * 2 + c;
            int mat = 1 + m * 3;
            k_conv<<<NB, 256, 0, stream>>>(hbh, rowptr, col,
                                           preH + (size_t)mat * 4096, preL + (size_t)mat * 4096,
                                           mlpb + (size_t)m * 3 * 64,
                                           z, stats + (size_t)sidx * 512, N);
            int last = (m == 3 && c == 1) ? 1 : 0;
            k_bnrelu<<<2048, 256, 0, stream>>>(
                (const float4*)z,
                stats + (size_t)sidx * 512, ngm + m * 64, nbt + m * 64,
                (float4*)res, (ushort4*)hbh, (ushort4*)hbl,
                (c == 1) ? 1 : 0, last, N * 16, invN);
        }

    // attention readout (v reuses z buffer — z is dead after last bnrelu)
    float* vbuf = z;
    k_vs<<<NB, 256, 0, stream>>>(hbh, hbl, preH + 13 * 4096, preL + 13 * 4096,
                                 Wk, seed, vbuf, scores, N);
    k_tail<<<G, 256, 0, stream>>>((const float4*)scores, vbuf, batch,
                                  Wo, predW, predb, emb, logits, N);
}